// Round 4
// baseline (792.263 us; speedup 1.0000x reference)
//
#include <hip/hip_runtime.h>
#include <hip/hip_bf16.h>
#include <math.h>

#define B_   16
#define CIN_ 256
#define H_   48
#define W_   48
#define N_   2304
#define K_   64
#define CD_  64

#define GAMMA_F 0.9999999999f

// ---------------- workspace layout (floats), total ~19.3 MiB ----------------
constexpr size_t OFF_XF    = 0;                                  // B*N*CD (xf; reused as Y after k_cov)
constexpr size_t OFF_ANT   = OFF_XF    + (size_t)B_*N_*CD_;      // B*K*N  raw attn, transposed
constexpr size_t OFF_T     = OFF_ANT   + (size_t)B_*K_*N_;       // K*CD
constexpr size_t OFF_T2    = OFF_T     + (size_t)K_*CD_;         // K
constexpr size_t OFF_LOGPI = OFF_T2    + K_;                     // K
constexpr size_t OFF_I2C   = OFF_LOGPI + K_;                     // K
constexpr size_t OFF_X2    = OFF_I2C   + K_;                     // B*N
constexpr size_t OFF_CS    = OFF_X2    + (size_t)B_*N_;          // B*K
constexpr size_t OFF_ICN   = OFF_CS    + (size_t)B_*K_;          // B*K
constexpr size_t OFF_TNEW  = OFF_ICN   + (size_t)B_*K_;          // B*K*CD
constexpr size_t OFF_TN2   = OFF_TNEW  + (size_t)B_*K_*CD_;      // B*K
constexpr size_t OFF_IMCOL = OFF_TN2   + (size_t)B_*K_;          // N (reciprocal col sums)

// ---------------- output layout (fp32 elements) ----------------
constexpr size_t OUT_OUTP = 0;
constexpr size_t OUT_ATTN = (size_t)B_*K_*N_;
constexpr size_t OUT_TNEW = OUT_ATTN + (size_t)B_*K_*N_;
constexpr size_t OUT_PI   = OUT_TNEW + (size_t)B_*K_*CD_;
constexpr size_t OUT_COV  = OUT_PI   + (size_t)B_*K_;

// ============ 1) projection: xf[b,n,c] = sum_i x[b,i,n]*w[c,i] ============
__global__ __launch_bounds__(256) void k_proj(const float* __restrict__ x, const float* __restrict__ wp,
                                              float* __restrict__ xf) {
  __shared__ float xs[32][64];
  __shared__ float ws_[32][65];
  int b = blockIdx.y, n0 = blockIdx.x * 64;
  int tid = threadIdx.x;
  int nn = tid & 63, cg = tid >> 6;
  float acc[16];
#pragma unroll
  for (int j = 0; j < 16; j++) acc[j] = 0.f;
  for (int i0 = 0; i0 < CIN_; i0 += 32) {
#pragma unroll
    for (int j = 0; j < 8; j++) {
      int ii = cg * 8 + j;
      xs[ii][nn] = x[((size_t)b * CIN_ + i0 + ii) * N_ + n0 + nn];
    }
    {
      int c = tid >> 2, iq = (tid & 3) * 8;
#pragma unroll
      for (int j = 0; j < 8; j++)
        ws_[iq + j][c] = wp[(size_t)c * CIN_ + i0 + iq + j];
    }
    __syncthreads();
#pragma unroll
    for (int ii = 0; ii < 32; ++ii) {
      float xv = xs[ii][nn];
#pragma unroll
      for (int j = 0; j < 16; j++) acc[j] += xv * ws_[ii][cg * 16 + j];
    }
    __syncthreads();
  }
  float* dst = xf + ((size_t)b * N_ + n0 + nn) * CD_ + cg * 16;
#pragma unroll
  for (int j4 = 0; j4 < 4; j4++)
    *(float4*)(dst + j4 * 4) = make_float4(acc[j4*4], acc[j4*4+1], acc[j4*4+2], acc[j4*4+3]);
}

// ============ 2) templates LN + per-k constants ============
__global__ void k_templ(const float* __restrict__ clusters, const float* __restrict__ pi,
                        const float* __restrict__ cov, const float* __restrict__ nsc,
                        const float* __restrict__ nbi, float* __restrict__ t, float* __restrict__ t2,
                        float* __restrict__ logpi, float* __restrict__ i2c) {
  int k = threadIdx.x;  // 64 threads
  float v[CD_];
  float m = 0;
#pragma unroll
  for (int c = 0; c < CD_; c++) { v[c] = clusters[k * CD_ + c]; m += v[c]; }
  m /= CD_;
  float var = 0;
#pragma unroll
  for (int c = 0; c < CD_; c++) { float d = v[c] - m; var += d * d; }
  var /= CD_;
  float inv = 1.f / sqrtf(var + 1e-5f);
  float s2 = 0;
#pragma unroll
  for (int c = 0; c < CD_; c++) {
    float tv = (v[c] - m) * inv * nsc[c] + nbi[c];
    t[k * CD_ + c] = tv;
    s2 += tv * tv;
  }
  t2[k] = s2;
  float p = pi[k], cv = cov[k];
  logpi[k] = logf(p) - 0.5f * logf(cv);
  i2c[k] = 0.5f / cv;
}

// ==== 3) distances + softmax; writes attn_out (fp32, [B,K,N]) + raw attn transposed + x2 ====
__global__ __launch_bounds__(256) void k_attn(const float* __restrict__ xf, const float* __restrict__ t,
                                              const float* __restrict__ t2, const float* __restrict__ logpi,
                                              const float* __restrict__ i2c, float* __restrict__ ant,
                                              float* __restrict__ aout, float* __restrict__ x2o) {
  __shared__ __align__(16) float ts[K_ * CD_];
  __shared__ float t2s[K_], lps[K_], ics[K_];
  int tid = threadIdx.x;
  for (int i = tid; i < K_ * CD_; i += 256) ts[i] = t[i];
  if (tid < K_) { t2s[tid] = t2[tid]; lps[tid] = logpi[tid]; ics[tid] = i2c[tid]; }
  __syncthreads();
  int b = blockIdx.y;
  int n = blockIdx.x * 256 + tid;
  const float4* xr = (const float4*)(xf + ((size_t)b * N_ + n) * CD_);
  float4 xv[16];
#pragma unroll
  for (int i = 0; i < 16; i++) xv[i] = xr[i];
  float x2 = 0;
#pragma unroll
  for (int i = 0; i < 16; i++) x2 += xv[i].x * xv[i].x + xv[i].y * xv[i].y + xv[i].z * xv[i].z + xv[i].w * xv[i].w;
  x2o[(size_t)b * N_ + n] = x2;
  float lg[K_];
#pragma unroll
  for (int k = 0; k < K_; k++) {
    const float4* tk = (const float4*)(ts + k * CD_);
    float dot = 0;
#pragma unroll
    for (int i = 0; i < 16; i++) {
      float4 tv = tk[i];
      dot += xv[i].x * tv.x + xv[i].y * tv.y + xv[i].z * tv.z + xv[i].w * tv.w;
    }
    lg[k] = lps[k] - (x2 + t2s[k] - 2.f * dot) * ics[k];
  }
  float mx = lg[0];
#pragma unroll
  for (int k = 1; k < K_; k++) mx = fmaxf(mx, lg[k]);
  float sum = 0;
#pragma unroll
  for (int k = 0; k < K_; k++) { lg[k] = __expf(lg[k] - mx); sum += lg[k]; }
  float inv = 1.f / sum;
  size_t base = (size_t)b * K_ * N_ + n;
#pragma unroll
  for (int k = 0; k < K_; k++) {
    float v = lg[k] * inv;
    ant[base + (size_t)k * N_] = v;
    aout[base + (size_t)k * N_] = v;
  }
}

// ============ 4) colsum[r] = sum_n ant[r,n],  r = b*K+k ============
__global__ __launch_bounds__(256) void k_colsum2(const float* __restrict__ ant, float* __restrict__ colsum) {
  int r = blockIdx.x, tid = threadIdx.x;
  const float* row = ant + (size_t)r * N_;
  float s = 0;
  for (int n = tid; n < N_; n += 256) s += row[n];
#pragma unroll
  for (int off = 32; off; off >>= 1) s += __shfl_down(s, off);
  __shared__ float red[4];
  if ((tid & 63) == 0) red[tid >> 6] = s;
  __syncthreads();
  if (tid == 0) colsum[r] = red[0] + red[1] + red[2] + red[3];
}

// ============ 5) pi_new + inverse normalizer ============
__global__ void k_pinew(const float* __restrict__ colsum, const float* __restrict__ pi,
                        float* __restrict__ pi_out, float* __restrict__ icn) {
  int b = blockIdx.x, k = threadIdx.x;
  float cs = colsum[b * K_ + k];
  float p = pi[k];
  pi_out[b * K_ + k] = p + GAMMA_F * (cs / (float)N_ - p);
  icn[b * K_ + k] = 1.f / (cs + (float)N_ * 1e-8f);
}

// ============ 6) t_new per (b,k) block ============
__global__ __launch_bounds__(256) void k_tnew(const float* __restrict__ ant, const float* __restrict__ icn,
                                              const float* __restrict__ xf,
                                              const float* __restrict__ clusters, float* __restrict__ tnew,
                                              float* __restrict__ tnew_out, float* __restrict__ tn2) {
  int k = blockIdx.x, b = blockIdx.y;
  int tid = threadIdx.x;
  int c = tid & 63, g = tid >> 6;
  const float* arow = ant + ((size_t)b * K_ + k) * N_;
  float acc = 0;
#pragma unroll 4
  for (int n = g; n < N_; n += 4)
    acc += (arow[n] + 1e-8f) * xf[((size_t)b * N_ + n) * CD_ + c];
  __shared__ float red[4][64];
  red[g][c] = acc;
  __syncthreads();
  if (tid < 64) {
    float s = (red[0][c] + red[1][c] + red[2][c] + red[3][c]) * icn[b * K_ + k];
    float cl = clusters[k * CD_ + c];
    float tv = cl + GAMMA_F * (s - cl);
    size_t o = ((size_t)b * K_ + k) * CD_ + c;
    tnew[o] = tv;
    tnew_out[o] = tv;
    float sq = tv * tv;
#pragma unroll
    for (int off = 32; off; off >>= 1) sq += __shfl_down(sq, off);
    if (c == 0) tn2[b * K_ + k] = sq;
  }
}

// ============ 7) cov_new per (b,k) block ============
__global__ __launch_bounds__(256) void k_cov(const float* __restrict__ xf, const float* __restrict__ ant,
                                             const float* __restrict__ icn,
                                             const float* __restrict__ tnew, const float* __restrict__ tn2,
                                             const float* __restrict__ x2, const float* __restrict__ cov,
                                             float* __restrict__ cov_out) {
  int k = blockIdx.x, b = blockIdx.y, tid = threadIdx.x;
  __shared__ __align__(16) float tns[CD_];
  if (tid < CD_) tns[tid] = tnew[((size_t)b * K_ + k) * CD_ + tid];
  __syncthreads();
  float tn2v = tn2[b * K_ + k];
  const float* arow = ant + ((size_t)b * K_ + k) * N_;
  const float* x2r = x2 + (size_t)b * N_;
  float acc = 0;
  for (int n = tid; n < N_; n += 256) {
    const float4* xr = (const float4*)(xf + ((size_t)b * N_ + n) * CD_);
    float dot = 0;
#pragma unroll
    for (int i = 0; i < 16; i++) {
      float4 xv = xr[i];
      float4 tv = ((const float4*)tns)[i];
      dot += xv.x * tv.x + xv.y * tv.y + xv.z * tv.z + xv.w * tv.w;
    }
    float d2v = x2r[n] + tn2v - 2.f * dot;
    acc += d2v * (arow[n] + 1e-8f);
  }
#pragma unroll
  for (int off = 32; off; off >>= 1) acc += __shfl_down(acc, off);
  __shared__ float red[4];
  if ((tid & 63) == 0) red[tid >> 6] = acc;
  __syncthreads();
  if (tid == 0) {
    float cv = cov[k];
    float s = (red[0] + red[1] + red[2] + red[3]) * icn[b * K_ + k];
    cov_out[b * K_ + k] = cv + GAMMA_F * (s - cv);
  }
}

// ============ 8) reciprocal mask column sums ============
__global__ __launch_bounds__(256) void k_msum(float* __restrict__ imcol) {
  int m = blockIdx.x;
  int mi = m / W_, mj = m % W_;
  float s = 0;
  for (int n = threadIdx.x; n < N_; n += 256) {
    int ni = n / W_, nj = n % W_;
    float dx = (float)(ni - mi), dy = (float)(nj - mj);
    s += __expf(-sqrtf(dx * dx + dy * dy));
  }
#pragma unroll
  for (int off = 32; off; off >>= 1) s += __shfl_down(s, off);
  __shared__ float red[4];
  if ((threadIdx.x & 63) == 0) red[threadIdx.x >> 6] = s;
  __syncthreads();
  if (threadIdx.x == 0) imcol[m] = 1.f / (red[0] + red[1] + red[2] + red[3]);
}

// ==== 9) gemm1: Y[r,m] = sum_n ((ant[r,n]+1e-8)*icn[r]) * A(n,m), A regenerated on the fly ====
__global__ __launch_bounds__(256) void gemm1(const float* __restrict__ Am, const float* __restrict__ icn,
                                             const float* __restrict__ imcol, float* __restrict__ Cm) {
  __shared__ float As[16][68];
  __shared__ float Bs[16][68];
  const int tid = threadIdx.x;
  const int m0 = blockIdx.y * 64, n0 = blockIdx.x * 64;
  const int tm = (tid >> 4) * 4, tn = (tid & 15) * 4;
  const int ar = tid >> 2, ak = (tid & 3) * 4;
  const int bk = tid >> 4, bn = (tid & 15) * 4;
  const float srow = icn[m0 + ar];
  const float badd = 1e-8f * srow;
  float acc[4][4] = {};
  for (int k0 = 0; k0 < N_; k0 += 16) {
    float4 av = *(const float4*)(Am + (size_t)(m0 + ar) * N_ + k0 + ak);
    {
      int nrow = k0 + bk;
      int ni = nrow / W_, nj = nrow - ni * W_;
#pragma unroll
      for (int j = 0; j < 4; j++) {
        int m = n0 + bn + j;
        int mi = m / W_, mj = m - mi * W_;
        float dx = (float)(ni - mi), dy = (float)(nj - mj);
        Bs[bk][bn + j] = __expf(-sqrtf(dx * dx + dy * dy)) * imcol[m];
      }
    }
    As[ak + 0][ar] = fmaf(av.x, srow, badd);
    As[ak + 1][ar] = fmaf(av.y, srow, badd);
    As[ak + 2][ar] = fmaf(av.z, srow, badd);
    As[ak + 3][ar] = fmaf(av.w, srow, badd);
    __syncthreads();
#pragma unroll
    for (int kk = 0; kk < 16; ++kk) {
      float a4[4], b4[4];
      *(float4*)a4 = *(const float4*)&As[kk][tm];
      *(float4*)b4 = *(const float4*)&Bs[kk][tn];
#pragma unroll
      for (int i = 0; i < 4; i++)
#pragma unroll
        for (int j = 0; j < 4; j++) acc[i][j] += a4[i] * b4[j];
    }
    __syncthreads();
  }
#pragma unroll
  for (int i = 0; i < 4; i++)
    *(float4*)(Cm + (size_t)(m0 + tm + i) * N_ + n0 + tn) =
        make_float4(acc[i][0], acc[i][1], acc[i][2], acc[i][3]);
}

// ==== 10) gemm2: outp_pre[b,k,m] = sum_n Y[b*K+k,n]*A(n,m); fused LN over k; fp32 out ====
__global__ __launch_bounds__(256) void gemm2_ln(const float* __restrict__ Ym, const float* __restrict__ imcol,
                                                const float* __restrict__ pns, const float* __restrict__ pnb,
                                                float* __restrict__ outp) {
  __shared__ float As[16][68];
  __shared__ float Bs[16][68];
  __shared__ float S[64][68];
  __shared__ float mu[64], rstd[64], sc[64], bi[64];
  const int tid = threadIdx.x;
  const int b = blockIdx.y;
  const int m0 = b * 64, n0 = blockIdx.x * 64;
  const int tm = (tid >> 4) * 4, tn = (tid & 15) * 4;
  const int ar = tid >> 2, ak = (tid & 3) * 4;
  const int bk = tid >> 4, bn = (tid & 15) * 4;
  if (tid < 64) { sc[tid] = pns[tid]; bi[tid] = pnb[tid]; }
  float acc[4][4] = {};
  for (int k0 = 0; k0 < N_; k0 += 16) {
    float4 av = *(const float4*)(Ym + (size_t)(m0 + ar) * N_ + k0 + ak);
    {
      int nrow = k0 + bk;
      int ni = nrow / W_, nj = nrow - ni * W_;
#pragma unroll
      for (int j = 0; j < 4; j++) {
        int m = n0 + bn + j;
        int mi = m / W_, mj = m - mi * W_;
        float dx = (float)(ni - mi), dy = (float)(nj - mj);
        Bs[bk][bn + j] = __expf(-sqrtf(dx * dx + dy * dy)) * imcol[m];
      }
    }
    As[ak + 0][ar] = av.x; As[ak + 1][ar] = av.y; As[ak + 2][ar] = av.z; As[ak + 3][ar] = av.w;
    __syncthreads();
#pragma unroll
    for (int kk = 0; kk < 16; ++kk) {
      float a4[4], b4[4];
      *(float4*)a4 = *(const float4*)&As[kk][tm];
      *(float4*)b4 = *(const float4*)&Bs[kk][tn];
#pragma unroll
      for (int i = 0; i < 4; i++)
#pragma unroll
        for (int j = 0; j < 4; j++) acc[i][j] += a4[i] * b4[j];
    }
    __syncthreads();
  }
#pragma unroll
  for (int i = 0; i < 4; i++)
#pragma unroll
    for (int j = 0; j < 4; j++) S[tm + i][tn + j] = acc[i][j];
  __syncthreads();
  if (tid < 64) {
    float s = 0;
#pragma unroll
    for (int k = 0; k < K_; k++) s += S[k][tid];
    float m = s / (float)K_;
    float v = 0;
#pragma unroll
    for (int k = 0; k < K_; k++) { float d = S[k][tid] - m; v += d * d; }
    v /= (float)K_;
    mu[tid] = m;
    rstd[tid] = 1.f / sqrtf(v + 1e-5f);
  }
  __syncthreads();
#pragma unroll
  for (int i = 0; i < 4; i++) {
    int k = tm + i;
    float* dst = outp + ((size_t)b * K_ + k) * N_ + n0 + tn;
    *(float4*)dst = make_float4(
        (acc[i][0] - mu[tn + 0]) * rstd[tn + 0] * sc[k] + bi[k],
        (acc[i][1] - mu[tn + 1]) * rstd[tn + 1] * sc[k] + bi[k],
        (acc[i][2] - mu[tn + 2]) * rstd[tn + 2] * sc[k] + bi[k],
        (acc[i][3] - mu[tn + 3]) * rstd[tn + 3] * sc[k] + bi[k]);
  }
}

extern "C" void kernel_launch(void* const* d_in, const int* in_sizes, int n_in,
                              void* d_out, int out_size, void* d_ws, size_t ws_size,
                              hipStream_t stream) {
  const float* x        = (const float*)d_in[0];
  const float* clusters = (const float*)d_in[1];
  const float* pi       = (const float*)d_in[2];
  const float* cov      = (const float*)d_in[3];
  const float* w_proj   = (const float*)d_in[4];
  const float* nt_scale = (const float*)d_in[5];
  const float* nt_bias  = (const float*)d_in[6];
  const float* pn_scale = (const float*)d_in[7];
  const float* pn_bias  = (const float*)d_in[8];
  float* out = (float*)d_out;
  float* w = (float*)d_ws;

  k_proj<<<dim3(N_ / 64, B_), 256, 0, stream>>>(x, w_proj, w + OFF_XF);
  k_templ<<<1, K_, 0, stream>>>(clusters, pi, cov, nt_scale, nt_bias,
                                w + OFF_T, w + OFF_T2, w + OFF_LOGPI, w + OFF_I2C);
  k_attn<<<dim3(N_ / 256, B_), 256, 0, stream>>>(w + OFF_XF, w + OFF_T, w + OFF_T2,
                                                 w + OFF_LOGPI, w + OFF_I2C,
                                                 w + OFF_ANT, out + OUT_ATTN, w + OFF_X2);
  k_colsum2<<<B_ * K_, 256, 0, stream>>>(w + OFF_ANT, w + OFF_CS);
  k_pinew<<<B_, K_, 0, stream>>>(w + OFF_CS, pi, out + OUT_PI, w + OFF_ICN);
  k_tnew<<<dim3(K_, B_), 256, 0, stream>>>(w + OFF_ANT, w + OFF_ICN, w + OFF_XF, clusters,
                                           w + OFF_TNEW, out + OUT_TNEW, w + OFF_TN2);
  k_cov<<<dim3(K_, B_), 256, 0, stream>>>(w + OFF_XF, w + OFF_ANT, w + OFF_ICN, w + OFF_TNEW,
                                          w + OFF_TN2, w + OFF_X2, cov, out + OUT_COV);
  k_msum<<<N_, 256, 0, stream>>>(w + OFF_IMCOL);
  gemm1<<<dim3(N_ / 64, (B_ * K_) / 64), 256, 0, stream>>>(w + OFF_ANT, w + OFF_ICN,
                                                           w + OFF_IMCOL, w + OFF_XF);
  gemm2_ln<<<dim3(N_ / 64, B_), 256, 0, stream>>>(w + OFF_XF, w + OFF_IMCOL,
                                                  pn_scale, pn_bias, out + OUT_OUTP);
}

// Round 8
// 597.612 us; speedup vs baseline: 1.3257x; 1.3257x over previous
//
#include <hip/hip_runtime.h>
#include <hip/hip_bf16.h>
#include <math.h>

#define B_   16
#define CIN_ 256
#define H_   48
#define W_   48
#define N_   2304
#define K_   64
#define CD_  64

#define GAMMA_F 0.9999999999f

using f32x4  = __attribute__((ext_vector_type(4))) float;
using bf16x8 = __attribute__((ext_vector_type(8))) short;

// fp32 -> (hi, lo) bf16 pair, RNE both times.
__device__ __forceinline__ void split_bf(float x, short& hi, short& lo) {
  unsigned u = __builtin_bit_cast(unsigned, x);
  unsigned r = (u + 0x7FFFu + ((u >> 16) & 1u)) & 0xFFFF0000u;
  hi = (short)(r >> 16);
  float res = x - __builtin_bit_cast(float, r);
  unsigned u2 = __builtin_bit_cast(unsigned, res);
  unsigned r2 = u2 + 0x7FFFu + ((u2 >> 16) & 1u);
  lo = (short)(r2 >> 16);
}

// ---------------- workspace layout (floats) ----------------
constexpr size_t OFF_XF    = 0;                                  // B*N*CD (xf; reused as Ydev)
constexpr size_t OFF_ANT   = OFF_XF    + (size_t)B_*N_*CD_;      // B*K*N  raw attn, transposed
constexpr size_t OFF_T     = OFF_ANT   + (size_t)B_*K_*N_;      // K*CD
constexpr size_t OFF_T2    = OFF_T     + (size_t)K_*CD_;         // K
constexpr size_t OFF_LOGPI = OFF_T2    + K_;                     // K
constexpr size_t OFF_I2C   = OFF_LOGPI + K_;                     // K
constexpr size_t OFF_X2    = OFF_I2C   + K_;                     // B*N (x2; reused as amean after k_cov)
constexpr size_t OFF_CS    = OFF_X2    + (size_t)B_*N_;          // B*K
constexpr size_t OFF_ICN   = OFF_CS    + (size_t)B_*K_;          // B*K
constexpr size_t OFF_TNEW  = OFF_ICN   + (size_t)B_*K_;          // B*K*CD
constexpr size_t OFF_TN2   = OFF_TNEW  + (size_t)B_*K_*CD_;      // B*K
constexpr size_t OFF_IMCOL = OFF_TN2   + (size_t)B_*K_;          // N (reciprocal col sums)

// ---------------- output layout (fp32 elements) ----------------
constexpr size_t OUT_OUTP = 0;
constexpr size_t OUT_ATTN = (size_t)B_*K_*N_;
constexpr size_t OUT_TNEW = OUT_ATTN + (size_t)B_*K_*N_;
constexpr size_t OUT_PI   = OUT_TNEW + (size_t)B_*K_*CD_;
constexpr size_t OUT_COV  = OUT_PI   + (size_t)B_*K_;

// ============ 1) projection: xf[b,n,c] = sum_i x[b,i,n]*w[c,i] ============
__global__ __launch_bounds__(256) void k_proj(const float* __restrict__ x, const float* __restrict__ wp,
                                              float* __restrict__ xf) {
  __shared__ float xs[32][64];
  __shared__ float ws_[32][65];
  int b = blockIdx.y, n0 = blockIdx.x * 64;
  int tid = threadIdx.x;
  int nn = tid & 63, cg = tid >> 6;
  float acc[16];
#pragma unroll
  for (int j = 0; j < 16; j++) acc[j] = 0.f;
  for (int i0 = 0; i0 < CIN_; i0 += 32) {
#pragma unroll
    for (int j = 0; j < 8; j++) {
      int ii = cg * 8 + j;
      xs[ii][nn] = x[((size_t)b * CIN_ + i0 + ii) * N_ + n0 + nn];
    }
    {
      int c = tid >> 2, iq = (tid & 3) * 8;
#pragma unroll
      for (int j = 0; j < 8; j++)
        ws_[iq + j][c] = wp[(size_t)c * CIN_ + i0 + iq + j];
    }
    __syncthreads();
#pragma unroll
    for (int ii = 0; ii < 32; ++ii) {
      float xv = xs[ii][nn];
#pragma unroll
      for (int j = 0; j < 16; j++) acc[j] += xv * ws_[ii][cg * 16 + j];
    }
    __syncthreads();
  }
  float* dst = xf + ((size_t)b * N_ + n0 + nn) * CD_ + cg * 16;
#pragma unroll
  for (int j4 = 0; j4 < 4; j4++)
    *(float4*)(dst + j4 * 4) = make_float4(acc[j4*4], acc[j4*4+1], acc[j4*4+2], acc[j4*4+3]);
}

// ============ 2) templates LN + per-k constants ============
__global__ void k_templ(const float* __restrict__ clusters, const float* __restrict__ pi,
                        const float* __restrict__ cov, const float* __restrict__ nsc,
                        const float* __restrict__ nbi, float* __restrict__ t, float* __restrict__ t2,
                        float* __restrict__ logpi, float* __restrict__ i2c) {
  int k = threadIdx.x;  // 64 threads
  float v[CD_];
  float m = 0;
#pragma unroll
  for (int c = 0; c < CD_; c++) { v[c] = clusters[k * CD_ + c]; m += v[c]; }
  m /= CD_;
  float var = 0;
#pragma unroll
  for (int c = 0; c < CD_; c++) { float d = v[c] - m; var += d * d; }
  var /= CD_;
  float inv = 1.f / sqrtf(var + 1e-5f);
  float s2 = 0;
#pragma unroll
  for (int c = 0; c < CD_; c++) {
    float tv = (v[c] - m) * inv * nsc[c] + nbi[c];
    t[k * CD_ + c] = tv;
    s2 += tv * tv;
  }
  t2[k] = s2;
  float p = pi[k], cv = cov[k];
  logpi[k] = logf(p) - 0.5f * logf(cv);
  i2c[k] = 0.5f / cv;
}

// ==== 3) distances + softmax; writes attn_out (fp32, [B,K,N]) + raw attn transposed + x2 ====
__global__ __launch_bounds__(256) void k_attn(const float* __restrict__ xf, const float* __restrict__ t,
                                              const float* __restrict__ t2, const float* __restrict__ logpi,
                                              const float* __restrict__ i2c, float* __restrict__ ant,
                                              float* __restrict__ aout, float* __restrict__ x2o) {
  __shared__ __align__(16) float ts[K_ * CD_];
  __shared__ float t2s[K_], lps[K_], ics[K_];
  int tid = threadIdx.x;
  for (int i = tid; i < K_ * CD_; i += 256) ts[i] = t[i];
  if (tid < K_) { t2s[tid] = t2[tid]; lps[tid] = logpi[tid]; ics[tid] = i2c[tid]; }
  __syncthreads();
  int b = blockIdx.y;
  int n = blockIdx.x * 256 + tid;
  const float4* xr = (const float4*)(xf + ((size_t)b * N_ + n) * CD_);
  float4 xv[16];
#pragma unroll
  for (int i = 0; i < 16; i++) xv[i] = xr[i];
  float x2 = 0;
#pragma unroll
  for (int i = 0; i < 16; i++) x2 += xv[i].x * xv[i].x + xv[i].y * xv[i].y + xv[i].z * xv[i].z + xv[i].w * xv[i].w;
  x2o[(size_t)b * N_ + n] = x2;
  float lg[K_];
#pragma unroll
  for (int k = 0; k < K_; k++) {
    const float4* tk = (const float4*)(ts + k * CD_);
    float dot = 0;
#pragma unroll
    for (int i = 0; i < 16; i++) {
      float4 tv = tk[i];
      dot += xv[i].x * tv.x + xv[i].y * tv.y + xv[i].z * tv.z + xv[i].w * tv.w;
    }
    lg[k] = lps[k] - (x2 + t2s[k] - 2.f * dot) * ics[k];
  }
  float mx = lg[0];
#pragma unroll
  for (int k = 1; k < K_; k++) mx = fmaxf(mx, lg[k]);
  float sum = 0;
#pragma unroll
  for (int k = 0; k < K_; k++) { lg[k] = __expf(lg[k] - mx); sum += lg[k]; }
  float inv = 1.f / sum;
  size_t base = (size_t)b * K_ * N_ + n;
#pragma unroll
  for (int k = 0; k < K_; k++) {
    float v = lg[k] * inv;
    ant[base + (size_t)k * N_] = v;
    aout[base + (size_t)k * N_] = v;
  }
}

// ============ 4) colsum[r] = sum_n ant[r,n],  r = b*K+k ============
__global__ __launch_bounds__(256) void k_colsum2(const float* __restrict__ ant, float* __restrict__ colsum) {
  int r = blockIdx.x, tid = threadIdx.x;
  const float* row = ant + (size_t)r * N_;
  float s = 0;
  for (int n = tid; n < N_; n += 256) s += row[n];
#pragma unroll
  for (int off = 32; off; off >>= 1) s += __shfl_down(s, off);
  __shared__ float red[4];
  if ((tid & 63) == 0) red[tid >> 6] = s;
  __syncthreads();
  if (tid == 0) colsum[r] = red[0] + red[1] + red[2] + red[3];
}

// ============ 5) pi_new + inverse normalizer ============
__global__ void k_pinew(const float* __restrict__ colsum, const float* __restrict__ pi,
                        float* __restrict__ pi_out, float* __restrict__ icn) {
  int b = blockIdx.x, k = threadIdx.x;
  float cs = colsum[b * K_ + k];
  float p = pi[k];
  pi_out[b * K_ + k] = p + GAMMA_F * (cs / (float)N_ - p);
  icn[b * K_ + k] = 1.f / (cs + (float)N_ * 1e-8f);
}

// ============ 6) t_new per (b,k) block ============
__global__ __launch_bounds__(256) void k_tnew(const float* __restrict__ ant, const float* __restrict__ icn,
                                              const float* __restrict__ xf,
                                              const float* __restrict__ clusters, float* __restrict__ tnew,
                                              float* __restrict__ tnew_out, float* __restrict__ tn2) {
  int k = blockIdx.x, b = blockIdx.y;
  int tid = threadIdx.x;
  int c = tid & 63, g = tid >> 6;
  const float* arow = ant + ((size_t)b * K_ + k) * N_;
  float acc = 0;
#pragma unroll 4
  for (int n = g; n < N_; n += 4)
    acc += (arow[n] + 1e-8f) * xf[((size_t)b * N_ + n) * CD_ + c];
  __shared__ float red[4][64];
  red[g][c] = acc;
  __syncthreads();
  if (tid < 64) {
    float s = (red[0][c] + red[1][c] + red[2][c] + red[3][c]) * icn[b * K_ + k];
    float cl = clusters[k * CD_ + c];
    float tv = cl + GAMMA_F * (s - cl);
    size_t o = ((size_t)b * K_ + k) * CD_ + c;
    tnew[o] = tv;
    tnew_out[o] = tv;
    float sq = tv * tv;
#pragma unroll
    for (int off = 32; off; off >>= 1) sq += __shfl_down(sq, off);
    if (c == 0) tn2[b * K_ + k] = sq;
  }
}

// ============ 7) cov_new per (b,k) block ============
__global__ __launch_bounds__(256) void k_cov(const float* __restrict__ xf, const float* __restrict__ ant,
                                             const float* __restrict__ icn,
                                             const float* __restrict__ tnew, const float* __restrict__ tn2,
                                             const float* __restrict__ x2, const float* __restrict__ cov,
                                             float* __restrict__ cov_out) {
  int k = blockIdx.x, b = blockIdx.y, tid = threadIdx.x;
  __shared__ __align__(16) float tns[CD_];
  if (tid < CD_) tns[tid] = tnew[((size_t)b * K_ + k) * CD_ + tid];
  __syncthreads();
  float tn2v = tn2[b * K_ + k];
  const float* arow = ant + ((size_t)b * K_ + k) * N_;
  const float* x2r = x2 + (size_t)b * N_;
  float acc = 0;
  for (int n = tid; n < N_; n += 256) {
    const float4* xr = (const float4*)(xf + ((size_t)b * N_ + n) * CD_);
    float dot = 0;
#pragma unroll
    for (int i = 0; i < 16; i++) {
      float4 xv = xr[i];
      float4 tv = ((const float4*)tns)[i];
      dot += xv.x * tv.x + xv.y * tv.y + xv.z * tv.z + xv.w * tv.w;
    }
    float d2v = x2r[n] + tn2v - 2.f * dot;
    acc += d2v * (arow[n] + 1e-8f);
  }
#pragma unroll
  for (int off = 32; off; off >>= 1) acc += __shfl_down(acc, off);
  __shared__ float red[4];
  if ((tid & 63) == 0) red[tid >> 6] = acc;
  __syncthreads();
  if (tid == 0) {
    float cv = cov[k];
    float s = (red[0] + red[1] + red[2] + red[3]) * icn[b * K_ + k];
    cov_out[b * K_ + k] = cv + GAMMA_F * (s - cv);
  }
}

// ==== 7.5) amean[b,n] = (1/64) sum_k (ant[b,k,n]+1e-8)*icn[b,k] ====
__global__ __launch_bounds__(256) void k_amean(const float* __restrict__ ant, const float* __restrict__ icn,
                                               float* __restrict__ amean) {
  int b = blockIdx.y;
  int n = blockIdx.x * 256 + threadIdx.x;
  const float* base = ant + (size_t)b * K_ * N_ + n;
  const float* ic = icn + b * K_;
  float s = 0;
#pragma unroll 8
  for (int k = 0; k < K_; k++)
    s += (base[(size_t)k * N_] + 1e-8f) * ic[k];
  amean[(size_t)b * N_ + n] = s * (1.f / (float)K_);
}

// ============ 8) reciprocal mask column sums ============
__global__ __launch_bounds__(256) void k_msum(float* __restrict__ imcol) {
  int m = blockIdx.x;
  int mi = m / W_, mj = m % W_;
  float s = 0;
  for (int n = threadIdx.x; n < N_; n += 256) {
    int ni = n / W_, nj = n % W_;
    float dx = (float)(ni - mi), dy = (float)(nj - mj);
    s += __expf(-sqrtf(dx * dx + dy * dy));
  }
#pragma unroll
  for (int off = 32; off; off >>= 1) s += __shfl_down(s, off);
  __shared__ float red[4];
  if ((threadIdx.x & 63) == 0) red[threadIdx.x >> 6] = s;
  __syncthreads();
  if (threadIdx.x == 0) imcol[m] = 1.f / (red[0] + red[1] + red[2] + red[3]);
}

// ================= bf16x3 split-precision MFMA GEMM pair =================
// CORRECTED epilogue (round-8): register acc[ns][reg] at lane (fr,quad) holds
// D[w*16 + fr][ns*16 + quad*4 + reg] — each lane owns ONE row and 4
// consecutive columns. (Both surviving layout hypotheses — C/D transposed or
// operand-role swap — imply exactly this placement; k-mappings cancel by
// permutation-invariance since A and B are staged with identical k-order.)

// ==== 9) gemm1: Ydev[r,m] = sum_n (ant_n[r,n] - amean[b,n]) * A(n,m) ====
__global__ __launch_bounds__(256) void gemm1_mfma(const float* __restrict__ Am, const float* __restrict__ icn,
                                                  const float* __restrict__ amean,
                                                  const float* __restrict__ imcol, float* __restrict__ Yd) {
  __shared__ __align__(16) short Ah[64][40];
  __shared__ __align__(16) short Al[64][40];
  __shared__ __align__(16) short Bh[64][40];
  __shared__ __align__(16) short Bl[64][40];
  const int tid = threadIdx.x;
  const int b = blockIdx.y;
  const int m0 = b * 64, n0 = blockIdx.x * 64;
  const int lane = tid & 63, w = tid >> 6;
  const int fr = lane & 15, quad = lane >> 4;
  const int srow = tid >> 2;          // A row 0..63
  const int skq  = (tid & 3) * 8;     // A k-offset {0,8,16,24}
  const int bcol = tid & 63;          // B col (output m) 0..63
  const int btq  = (tid >> 6) * 8;    // B token-offset {0,8,16,24}
  const int colg = n0 + bcol;
  const int mi = colg / W_, mj = colg - (colg / W_) * W_;
  const float imc = imcol[colg];
  const float ic = icn[m0 + srow];
  const float badd = 1e-8f * ic;
  f32x4 acc[4] = {};
  for (int k0 = 0; k0 < N_; k0 += 32) {
    // stage A: centered values -> hi/lo bf16
    const float* ap = Am + (size_t)(m0 + srow) * N_ + k0 + skq;
    const float* mp = amean + (size_t)b * N_ + k0 + skq;
    float va[8];
    {
      float4 a0 = *(const float4*)ap;
      float4 a1 = *(const float4*)(ap + 4);
      float4 u0 = *(const float4*)mp;
      float4 u1 = *(const float4*)(mp + 4);
      va[0] = fmaf(a0.x, ic, badd) - u0.x; va[1] = fmaf(a0.y, ic, badd) - u0.y;
      va[2] = fmaf(a0.z, ic, badd) - u0.z; va[3] = fmaf(a0.w, ic, badd) - u0.w;
      va[4] = fmaf(a1.x, ic, badd) - u1.x; va[5] = fmaf(a1.y, ic, badd) - u1.y;
      va[6] = fmaf(a1.z, ic, badd) - u1.z; va[7] = fmaf(a1.w, ic, badd) - u1.w;
    }
    bf16x8 avh, avl;
#pragma unroll
    for (int j = 0; j < 8; j++) { short h, l; split_bf(va[j], h, l); avh[j] = h; avl[j] = l; }
    *(bf16x8*)&Ah[srow][skq] = avh;
    *(bf16x8*)&Al[srow][skq] = avl;
    // stage B^T: A(token,col) = exp(-dist)*imcol[col] -> hi/lo
    bf16x8 bvh, bvl;
#pragma unroll
    for (int j = 0; j < 8; j++) {
      int token = k0 + btq + j;
      int ni = token / W_, nj = token - (token / W_) * W_;
      float dx = (float)(ni - mi), dy = (float)(nj - mj);
      short h, l; split_bf(__expf(-sqrtf(dx * dx + dy * dy)) * imc, h, l);
      bvh[j] = h; bvl[j] = l;
    }
    *(bf16x8*)&Bh[bcol][btq] = bvh;
    *(bf16x8*)&Bl[bcol][btq] = bvl;
    __syncthreads();
    bf16x8 afh = *(const bf16x8*)&Ah[w * 16 + fr][quad * 8];
    bf16x8 afl = *(const bf16x8*)&Al[w * 16 + fr][quad * 8];
#pragma unroll
    for (int ns = 0; ns < 4; ns++) {
      bf16x8 bfh = *(const bf16x8*)&Bh[ns * 16 + fr][quad * 8];
      bf16x8 bfl = *(const bf16x8*)&Bl[ns * 16 + fr][quad * 8];
      acc[ns] = __builtin_amdgcn_mfma_f32_16x16x32_bf16(afh, bfh, acc[ns], 0, 0, 0);
      acc[ns] = __builtin_amdgcn_mfma_f32_16x16x32_bf16(afh, bfl, acc[ns], 0, 0, 0);
      acc[ns] = __builtin_amdgcn_mfma_f32_16x16x32_bf16(afl, bfh, acc[ns], 0, 0, 0);
    }
    __syncthreads();
  }
  // corrected epilogue: lane owns row w*16+fr, cols ns*16+quad*4..+3
#pragma unroll
  for (int ns = 0; ns < 4; ns++)
    *(f32x4*)&Yd[(size_t)(m0 + w * 16 + fr) * N_ + n0 + ns * 16 + quad * 4] = acc[ns];
}

// ==== 10) gemm2: D = Ydev @ A == outp_pre - mu_k; outp = D*rstd*sc + bi ====
__global__ __launch_bounds__(256) void gemm2_ln_mfma(const float* __restrict__ Yd, const float* __restrict__ imcol,
                                                     const float* __restrict__ pns, const float* __restrict__ pnb,
                                                     float* __restrict__ outp) {
  __shared__ __align__(16) short Ah[64][40];
  __shared__ __align__(16) short Al[64][40];
  __shared__ __align__(16) short Bh[64][40];
  __shared__ __align__(16) short Bl[64][40];
  __shared__ __align__(16) float S[64][68];
  __shared__ float rstd[64], sc[64], bi[64];
  const int tid = threadIdx.x;
  const int b = blockIdx.y;
  const int m0 = b * 64, n0 = blockIdx.x * 64;
  const int lane = tid & 63, w = tid >> 6;
  const int fr = lane & 15, quad = lane >> 4;
  const int srow = tid >> 2;
  const int skq  = (tid & 3) * 8;
  const int bcol = tid & 63;
  const int btq  = (tid >> 6) * 8;
  const int colg = n0 + bcol;
  const int mi = colg / W_, mj = colg - (colg / W_) * W_;
  const float imc = imcol[colg];
  if (tid < 64) { sc[tid] = pns[tid]; bi[tid] = pnb[tid]; }
  f32x4 acc[4] = {};
  for (int k0 = 0; k0 < N_; k0 += 32) {
    const float* ap = Yd + (size_t)(m0 + srow) * N_ + k0 + skq;
    float4 a0 = *(const float4*)ap;
    float4 a1 = *(const float4*)(ap + 4);
    float va[8] = {a0.x, a0.y, a0.z, a0.w, a1.x, a1.y, a1.z, a1.w};
    bf16x8 avh, avl;
#pragma unroll
    for (int j = 0; j < 8; j++) { short h, l; split_bf(va[j], h, l); avh[j] = h; avl[j] = l; }
    *(bf16x8*)&Ah[srow][skq] = avh;
    *(bf16x8*)&Al[srow][skq] = avl;
    bf16x8 bvh, bvl;
#pragma unroll
    for (int j = 0; j < 8; j++) {
      int token = k0 + btq + j;
      int ni = token / W_, nj = token - (token / W_) * W_;
      float dx = (float)(ni - mi), dy = (float)(nj - mj);
      short h, l; split_bf(__expf(-sqrtf(dx * dx + dy * dy)) * imc, h, l);
      bvh[j] = h; bvl[j] = l;
    }
    *(bf16x8*)&Bh[bcol][btq] = bvh;
    *(bf16x8*)&Bl[bcol][btq] = bvl;
    __syncthreads();
    bf16x8 afh = *(const bf16x8*)&Ah[w * 16 + fr][quad * 8];
    bf16x8 afl = *(const bf16x8*)&Al[w * 16 + fr][quad * 8];
#pragma unroll
    for (int ns = 0; ns < 4; ns++) {
      bf16x8 bfh = *(const bf16x8*)&Bh[ns * 16 + fr][quad * 8];
      bf16x8 bfl = *(const bf16x8*)&Bl[ns * 16 + fr][quad * 8];
      acc[ns] = __builtin_amdgcn_mfma_f32_16x16x32_bf16(afh, bfh, acc[ns], 0, 0, 0);
      acc[ns] = __builtin_amdgcn_mfma_f32_16x16x32_bf16(afh, bfl, acc[ns], 0, 0, 0);
      acc[ns] = __builtin_amdgcn_mfma_f32_16x16x32_bf16(afl, bfh, acc[ns], 0, 0, 0);
    }
    __syncthreads();
  }
  // corrected orientation: S[k_row][m_col]; D has zero k-mean -> var = mean_k(D^2)
#pragma unroll
  for (int ns = 0; ns < 4; ns++)
    *(f32x4*)&S[w * 16 + fr][ns * 16 + quad * 4] = acc[ns];
  __syncthreads();
  if (tid < 64) {
    float ss = 0;
#pragma unroll
    for (int k = 0; k < K_; k++) { float d = S[k][tid]; ss += d * d; }
    rstd[tid] = 1.f / sqrtf(ss / (float)K_ + 1e-5f);
  }
  __syncthreads();
  {
    int c = tid & 63, g = tid >> 6;
#pragma unroll
    for (int i = 0; i < 16; i++) {
      int r = g * 16 + i;
      outp[(size_t)(m0 + r) * N_ + n0 + c] = S[r][c] * rstd[c] * sc[r] + bi[r];
    }
  }
}

extern "C" void kernel_launch(void* const* d_in, const int* in_sizes, int n_in,
                              void* d_out, int out_size, void* d_ws, size_t ws_size,
                              hipStream_t stream) {
  const float* x        = (const float*)d_in[0];
  const float* clusters = (const float*)d_in[1];
  const float* pi       = (const float*)d_in[2];
  const float* cov      = (const float*)d_in[3];
  const float* w_proj   = (const float*)d_in[4];
  const float* nt_scale = (const float*)d_in[5];
  const float* nt_bias  = (const float*)d_in[6];
  const float* pn_scale = (const float*)d_in[7];
  const float* pn_bias  = (const float*)d_in[8];
  float* out = (float*)d_out;
  float* w = (float*)d_ws;

  k_proj<<<dim3(N_ / 64, B_), 256, 0, stream>>>(x, w_proj, w + OFF_XF);
  k_templ<<<1, K_, 0, stream>>>(clusters, pi, cov, nt_scale, nt_bias,
                                w + OFF_T, w + OFF_T2, w + OFF_LOGPI, w + OFF_I2C);
  k_attn<<<dim3(N_ / 256, B_), 256, 0, stream>>>(w + OFF_XF, w + OFF_T, w + OFF_T2,
                                                 w + OFF_LOGPI, w + OFF_I2C,
                                                 w + OFF_ANT, out + OUT_ATTN, w + OFF_X2);
  k_colsum2<<<B_ * K_, 256, 0, stream>>>(w + OFF_ANT, w + OFF_CS);
  k_pinew<<<B_, K_, 0, stream>>>(w + OFF_CS, pi, out + OUT_PI, w + OFF_ICN);
  k_tnew<<<dim3(K_, B_), 256, 0, stream>>>(w + OFF_ANT, w + OFF_ICN, w + OFF_XF, clusters,
                                           w + OFF_TNEW, out + OUT_TNEW, w + OFF_TN2);
  k_cov<<<dim3(K_, B_), 256, 0, stream>>>(w + OFF_XF, w + OFF_ANT, w + OFF_ICN, w + OFF_TNEW,
                                          w + OFF_TN2, w + OFF_X2, cov, out + OUT_COV);
  // amean reuses the x2 buffer (dead after k_cov)
  k_amean<<<dim3(N_ / 256, B_), 256, 0, stream>>>(w + OFF_ANT, w + OFF_ICN, w + OFF_X2);
  k_msum<<<N_, 256, 0, stream>>>(w + OFF_IMCOL);
  // Ydev = (attn_n - mean_k attn_n) @ A  (overwrites xf, dead after k_cov)
  gemm1_mfma<<<dim3(N_ / 64, B_), 256, 0, stream>>>(w + OFF_ANT, w + OFF_ICN, w + OFF_X2,
                                                    w + OFF_IMCOL, w + OFF_XF);
  // outp = (Ydev @ A) * rstd * sc + bi
  gemm2_ln_mfma<<<dim3(N_ / 64, B_), 256, 0, stream>>>(w + OFF_XF, w + OFF_IMCOL,
                                                       pn_scale, pn_bias, out + OUT_OUTP);
}

// Round 9
// 485.636 us; speedup vs baseline: 1.6314x; 1.2306x over previous
//
#include <hip/hip_runtime.h>
#include <hip/hip_bf16.h>
#include <math.h>

#define B_   16
#define CIN_ 256
#define H_   48
#define W_   48
#define N_   2304
#define K_   64
#define CD_  64

#define GAMMA_F 0.9999999999f
#define LUT_N  4419   // max d^2 = 2*47^2 = 4418

using f32x4  = __attribute__((ext_vector_type(4))) float;
using bf16x8 = __attribute__((ext_vector_type(8))) short;
using s16x4  = __attribute__((ext_vector_type(4))) short;

// fp32 -> (hi, lo) bf16 pair, RNE both times.
__device__ __forceinline__ void split_bf(float x, short& hi, short& lo) {
  unsigned u = __builtin_bit_cast(unsigned, x);
  unsigned r = (u + 0x7FFFu + ((u >> 16) & 1u)) & 0xFFFF0000u;
  hi = (short)(r >> 16);
  float res = x - __builtin_bit_cast(float, r);
  unsigned u2 = __builtin_bit_cast(unsigned, res);
  unsigned r2 = u2 + 0x7FFFu + ((u2 >> 16) & 1u);
  lo = (short)(r2 >> 16);
}

// ---------------- workspace layout (floats), ~19.3 MiB ----------------
constexpr size_t OFF_XF    = 0;                                  // B*N*CD (xf; later YdH/YdL bf16 planes)
constexpr size_t OFF_ANT   = OFF_XF    + (size_t)B_*N_*CD_;      // B*K*N  raw attn, transposed
constexpr size_t OFF_T     = OFF_ANT   + (size_t)B_*K_*N_;       // K*CD
constexpr size_t OFF_T2    = OFF_T     + (size_t)K_*CD_;         // K
constexpr size_t OFF_LOGPI = OFF_T2    + K_;                     // K
constexpr size_t OFF_I2C   = OFF_LOGPI + K_;                     // K
constexpr size_t OFF_X2    = OFF_I2C   + K_;                     // B*N (x2; reused as amean after k_tnew)
constexpr size_t OFF_CS    = OFF_X2    + (size_t)B_*N_;          // B*K
constexpr size_t OFF_ICN   = OFF_CS    + (size_t)B_*K_;          // B*K
constexpr size_t OFF_IMCOL = OFF_ICN   + (size_t)B_*K_;          // N (reciprocal col sums)

// ---------------- output layout (fp32 elements) ----------------
constexpr size_t OUT_OUTP = 0;
constexpr size_t OUT_ATTN = (size_t)B_*K_*N_;
constexpr size_t OUT_TNEW = OUT_ATTN + (size_t)B_*K_*N_;
constexpr size_t OUT_PI   = OUT_TNEW + (size_t)B_*K_*CD_;
constexpr size_t OUT_COV  = OUT_PI   + (size_t)B_*K_;

// ============ 1) projection: xf[b,n,c] = sum_i x[b,i,n]*w[c,i] ============
__global__ __launch_bounds__(256) void k_proj(const float* __restrict__ x, const float* __restrict__ wp,
                                              float* __restrict__ xf) {
  __shared__ float xs[32][64];
  __shared__ float ws_[32][65];
  int b = blockIdx.y, n0 = blockIdx.x * 64;
  int tid = threadIdx.x;
  int nn = tid & 63, cg = tid >> 6;
  float acc[16];
#pragma unroll
  for (int j = 0; j < 16; j++) acc[j] = 0.f;
  for (int i0 = 0; i0 < CIN_; i0 += 32) {
#pragma unroll
    for (int j = 0; j < 8; j++) {
      int ii = cg * 8 + j;
      xs[ii][nn] = x[((size_t)b * CIN_ + i0 + ii) * N_ + n0 + nn];
    }
    {
      int c = tid >> 2, iq = (tid & 3) * 8;
#pragma unroll
      for (int j = 0; j < 8; j++)
        ws_[iq + j][c] = wp[(size_t)c * CIN_ + i0 + iq + j];
    }
    __syncthreads();
#pragma unroll
    for (int ii = 0; ii < 32; ++ii) {
      float xv = xs[ii][nn];
#pragma unroll
      for (int j = 0; j < 16; j++) acc[j] += xv * ws_[ii][cg * 16 + j];
    }
    __syncthreads();
  }
  float* dst = xf + ((size_t)b * N_ + n0 + nn) * CD_ + cg * 16;
#pragma unroll
  for (int j4 = 0; j4 < 4; j4++)
    *(float4*)(dst + j4 * 4) = make_float4(acc[j4*4], acc[j4*4+1], acc[j4*4+2], acc[j4*4+3]);
}

// ============ 2) templates LN + per-k constants ============
__global__ void k_templ(const float* __restrict__ clusters, const float* __restrict__ pi,
                        const float* __restrict__ cov, const float* __restrict__ nsc,
                        const float* __restrict__ nbi, float* __restrict__ t, float* __restrict__ t2,
                        float* __restrict__ logpi, float* __restrict__ i2c) {
  int k = threadIdx.x;  // 64 threads
  float v[CD_];
  float m = 0;
#pragma unroll
  for (int c = 0; c < CD_; c++) { v[c] = clusters[k * CD_ + c]; m += v[c]; }
  m /= CD_;
  float var = 0;
#pragma unroll
  for (int c = 0; c < CD_; c++) { float d = v[c] - m; var += d * d; }
  var /= CD_;
  float inv = 1.f / sqrtf(var + 1e-5f);
  float s2 = 0;
#pragma unroll
  for (int c = 0; c < CD_; c++) {
    float tv = (v[c] - m) * inv * nsc[c] + nbi[c];
    t[k * CD_ + c] = tv;
    s2 += tv * tv;
  }
  t2[k] = s2;
  float p = pi[k], cv = cov[k];
  logpi[k] = logf(p) - 0.5f * logf(cv);
  i2c[k] = 0.5f / cv;
}

// ==== 3) distances + softmax; writes attn_out (fp32, [B,K,N]) + raw attn transposed + x2 ====
__global__ __launch_bounds__(256) void k_attn(const float* __restrict__ xf, const float* __restrict__ t,
                                              const float* __restrict__ t2, const float* __restrict__ logpi,
                                              const float* __restrict__ i2c, float* __restrict__ ant,
                                              float* __restrict__ aout, float* __restrict__ x2o) {
  __shared__ __align__(16) float ts[K_ * CD_];
  __shared__ float t2s[K_], lps[K_], ics[K_];
  int tid = threadIdx.x;
  for (int i = tid; i < K_ * CD_; i += 256) ts[i] = t[i];
  if (tid < K_) { t2s[tid] = t2[tid]; lps[tid] = logpi[tid]; ics[tid] = i2c[tid]; }
  __syncthreads();
  int b = blockIdx.y;
  int n = blockIdx.x * 256 + tid;
  const float4* xr = (const float4*)(xf + ((size_t)b * N_ + n) * CD_);
  float4 xv[16];
#pragma unroll
  for (int i = 0; i < 16; i++) xv[i] = xr[i];
  float x2 = 0;
#pragma unroll
  for (int i = 0; i < 16; i++) x2 += xv[i].x * xv[i].x + xv[i].y * xv[i].y + xv[i].z * xv[i].z + xv[i].w * xv[i].w;
  x2o[(size_t)b * N_ + n] = x2;
  float lg[K_];
#pragma unroll
  for (int k = 0; k < K_; k++) {
    const float4* tk = (const float4*)(ts + k * CD_);
    float dot = 0;
#pragma unroll
    for (int i = 0; i < 16; i++) {
      float4 tv = tk[i];
      dot += xv[i].x * tv.x + xv[i].y * tv.y + xv[i].z * tv.z + xv[i].w * tv.w;
    }
    lg[k] = lps[k] - (x2 + t2s[k] - 2.f * dot) * ics[k];
  }
  float mx = lg[0];
#pragma unroll
  for (int k = 1; k < K_; k++) mx = fmaxf(mx, lg[k]);
  float sum = 0;
#pragma unroll
  for (int k = 0; k < K_; k++) { lg[k] = __expf(lg[k] - mx); sum += lg[k]; }
  float inv = 1.f / sum;
  size_t base = (size_t)b * K_ * N_ + n;
#pragma unroll
  for (int k = 0; k < K_; k++) {
    float v = lg[k] * inv;
    ant[base + (size_t)k * N_] = v;
    aout[base + (size_t)k * N_] = v;
  }
}

// ============ 4) colsum[r] = sum_n ant[r,n],  r = b*K+k ============
__global__ __launch_bounds__(256) void k_colsum2(const float* __restrict__ ant, float* __restrict__ colsum) {
  int r = blockIdx.x, tid = threadIdx.x;
  const float* row = ant + (size_t)r * N_;
  float s = 0;
  for (int n = tid; n < N_; n += 256) s += row[n];
#pragma unroll
  for (int off = 32; off; off >>= 1) s += __shfl_down(s, off);
  __shared__ float red[4];
  if ((tid & 63) == 0) red[tid >> 6] = s;
  __syncthreads();
  if (tid == 0) colsum[r] = red[0] + red[1] + red[2] + red[3];
}

// ============ 5) pi_new + inverse normalizer ============
__global__ void k_pinew(const float* __restrict__ colsum, const float* __restrict__ pi,
                        float* __restrict__ pi_out, float* __restrict__ icn) {
  int b = blockIdx.x, k = threadIdx.x;
  float cs = colsum[b * K_ + k];
  float p = pi[k];
  pi_out[b * K_ + k] = p + GAMMA_F * (cs / (float)N_ - p);
  icn[b * K_ + k] = 1.f / (cs + (float)N_ * 1e-8f);
}

// ==== 6) t_new + cov fused per (b,k): cov via exact identity
//      sum_n a_n d2_n = sum_n a_n x2_n + |t_new|^2 - 2<s, t_new>  (sum_n a_n = 1) ====
__global__ __launch_bounds__(256) void k_tnew_cov(const float* __restrict__ ant, const float* __restrict__ icn,
                                                  const float* __restrict__ xf, const float* __restrict__ x2,
                                                  const float* __restrict__ clusters, const float* __restrict__ cov,
                                                  float* __restrict__ tnew_out, float* __restrict__ cov_out) {
  int k = blockIdx.x, b = blockIdx.y;
  int tid = threadIdx.x;
  int c = tid & 63, g = tid >> 6;
  const float* arow = ant + ((size_t)b * K_ + k) * N_;
  const float* x2r = x2 + (size_t)b * N_;
  float acc = 0, ax2 = 0;
#pragma unroll 4
  for (int n = g; n < N_; n += 4) {
    float a = arow[n] + 1e-8f;
    acc += a * xf[((size_t)b * N_ + n) * CD_ + c];
    ax2 += a * x2r[n];
  }
  __shared__ float red[4][64];
  __shared__ float red2[4];
  red[g][c] = acc;
  if (c == 0) red2[g] = ax2;   // ax2 identical across c within a group
  __syncthreads();
  if (tid < 64) {
    float icnv = icn[b * K_ + k];
    float s = (red[0][c] + red[1][c] + red[2][c] + red[3][c]) * icnv;
    float cl = clusters[k * CD_ + c];
    float tv = cl + GAMMA_F * (s - cl);
    tnew_out[((size_t)b * K_ + k) * CD_ + c] = tv;
    float sq = tv * tv;
    float st = s * tv;
#pragma unroll
    for (int off = 32; off; off >>= 1) { sq += __shfl_down(sq, off); st += __shfl_down(st, off); }
    if (c == 0) {
      float ax2t = (red2[0] + red2[1] + red2[2] + red2[3]) * icnv;
      float cv = cov[k];
      float csum = ax2t + sq - 2.f * st;
      cov_out[b * K_ + k] = cv + GAMMA_F * (csum - cv);
    }
  }
}

// ==== 7) amean[b,n] = (1/64) sum_k (ant[b,k,n]+1e-8)*icn[b,k] ====
__global__ __launch_bounds__(256) void k_amean(const float* __restrict__ ant, const float* __restrict__ icn,
                                               float* __restrict__ amean) {
  int b = blockIdx.y;
  int n = blockIdx.x * 256 + threadIdx.x;
  const float* base = ant + (size_t)b * K_ * N_ + n;
  const float* ic = icn + b * K_;
  float s = 0;
#pragma unroll 8
  for (int k = 0; k < K_; k++)
    s += (base[(size_t)k * N_] + 1e-8f) * ic[k];
  amean[(size_t)b * N_ + n] = s * (1.f / (float)K_);
}

// ============ 8) reciprocal mask column sums ============
__global__ __launch_bounds__(256) void k_msum(float* __restrict__ imcol) {
  int m = blockIdx.x;
  int mi = m / W_, mj = m % W_;
  float s = 0;
  for (int n = threadIdx.x; n < N_; n += 256) {
    int ni = n / W_, nj = n % W_;
    float dx = (float)(ni - mi), dy = (float)(nj - mj);
    s += __expf(-sqrtf(dx * dx + dy * dy));
  }
#pragma unroll
  for (int off = 32; off; off >>= 1) s += __shfl_down(s, off);
  __shared__ float red[4];
  if ((threadIdx.x & 63) == 0) red[threadIdx.x >> 6] = s;
  __syncthreads();
  if (threadIdx.x == 0) imcol[m] = 1.f / (red[0] + red[1] + red[2] + red[3]);
}

// ================= bf16x3 split-precision MFMA GEMM pair =================
// - exp/sqrt replaced by an integer-d^2 LUT in LDS (bit-identical fp chain)
// - gemm1 emits Yd as bf16 hi/lo planes; gemm2's A-staging is pure loads
// - C/D placement (verified round-8): lane (fr,quad) of wave w holds
//   D[w*16+fr][ns*16+quad*4+reg]

// ==== 9) gemm1: Ydev[r,m] = sum_n (ant_n[r,n] - amean[b,n]) * A(n,m) ====
__global__ __launch_bounds__(256) void gemm1_mfma(const float* __restrict__ Am, const float* __restrict__ icn,
                                                  const float* __restrict__ amean,
                                                  const float* __restrict__ imcol,
                                                  short* __restrict__ YdH, short* __restrict__ YdL) {
  __shared__ __align__(16) short Ah[64][40];
  __shared__ __align__(16) short Al[64][40];
  __shared__ __align__(16) short Bh[64][40];
  __shared__ __align__(16) short Bl[64][40];
  __shared__ float lut[LUT_N];
  const int tid = threadIdx.x;
  const int b = blockIdx.y;
  const int m0 = b * 64, n0 = blockIdx.x * 64;
  const int lane = tid & 63, w = tid >> 6;
  const int fr = lane & 15, quad = lane >> 4;
  const int srow = tid >> 2;          // A row 0..63
  const int skq  = (tid & 3) * 8;     // A k-offset {0,8,16,24}
  const int bcol = tid & 63;          // B col (output m) 0..63
  const int btq  = (tid >> 6) * 8;    // B token-offset {0,8,16,24}
  const int colg = n0 + bcol;
  const int mi = colg / W_, mj = colg - (colg / W_) * W_;
  const float imc = imcol[colg];
  const float ic = icn[m0 + srow];
  const float badd = 1e-8f * ic;
  for (int i = tid; i < LUT_N; i += 256) lut[i] = __expf(-sqrtf((float)i));
  __syncthreads();
  f32x4 acc[4] = {};
  for (int k0 = 0; k0 < N_; k0 += 32) {
    // stage A: centered values -> hi/lo bf16
    const float* ap = Am + (size_t)(m0 + srow) * N_ + k0 + skq;
    const float* mp = amean + (size_t)b * N_ + k0 + skq;
    float va[8];
    {
      float4 a0 = *(const float4*)ap;
      float4 a1 = *(const float4*)(ap + 4);
      float4 u0 = *(const float4*)mp;
      float4 u1 = *(const float4*)(mp + 4);
      va[0] = fmaf(a0.x, ic, badd) - u0.x; va[1] = fmaf(a0.y, ic, badd) - u0.y;
      va[2] = fmaf(a0.z, ic, badd) - u0.z; va[3] = fmaf(a0.w, ic, badd) - u0.w;
      va[4] = fmaf(a1.x, ic, badd) - u1.x; va[5] = fmaf(a1.y, ic, badd) - u1.y;
      va[6] = fmaf(a1.z, ic, badd) - u1.z; va[7] = fmaf(a1.w, ic, badd) - u1.w;
    }
    bf16x8 avh, avl;
#pragma unroll
    for (int j = 0; j < 8; j++) { short h, l; split_bf(va[j], h, l); avh[j] = h; avl[j] = l; }
    *(bf16x8*)&Ah[srow][skq] = avh;
    *(bf16x8*)&Al[srow][skq] = avl;
    // stage B^T via LUT: A(token,col) = lut[d2]*imcol[col] -> hi/lo
    bf16x8 bvh, bvl;
#pragma unroll
    for (int j = 0; j < 8; j++) {
      int token = k0 + btq + j;
      int ni = token / W_, nj = token - (token / W_) * W_;
      int dxi = ni - mi, dyi = nj - mj;
      int d2 = dxi * dxi + dyi * dyi;
      short h, l; split_bf(lut[d2] * imc, h, l);
      bvh[j] = h; bvl[j] = l;
    }
    *(bf16x8*)&Bh[bcol][btq] = bvh;
    *(bf16x8*)&Bl[bcol][btq] = bvl;
    __syncthreads();
    bf16x8 afh = *(const bf16x8*)&Ah[w * 16 + fr][quad * 8];
    bf16x8 afl = *(const bf16x8*)&Al[w * 16 + fr][quad * 8];
#pragma unroll
    for (int ns = 0; ns < 4; ns++) {
      bf16x8 bfh = *(const bf16x8*)&Bh[ns * 16 + fr][quad * 8];
      bf16x8 bfl = *(const bf16x8*)&Bl[ns * 16 + fr][quad * 8];
      acc[ns] = __builtin_amdgcn_mfma_f32_16x16x32_bf16(afh, bfh, acc[ns], 0, 0, 0);
      acc[ns] = __builtin_amdgcn_mfma_f32_16x16x32_bf16(afh, bfl, acc[ns], 0, 0, 0);
      acc[ns] = __builtin_amdgcn_mfma_f32_16x16x32_bf16(afl, bfh, acc[ns], 0, 0, 0);
    }
    __syncthreads();
  }
  // epilogue: split acc -> bf16 hi/lo planes (row w*16+fr, cols ns*16+quad*4..+3)
  const size_t rbase = (size_t)(m0 + w * 16 + fr) * N_ + n0;
#pragma unroll
  for (int ns = 0; ns < 4; ns++) {
    s16x4 h4, l4;
#pragma unroll
    for (int reg = 0; reg < 4; reg++) { short h, l; split_bf(acc[ns][reg], h, l); h4[reg] = h; l4[reg] = l; }
    *(s16x4*)&YdH[rbase + ns * 16 + quad * 4] = h4;
    *(s16x4*)&YdL[rbase + ns * 16 + quad * 4] = l4;
  }
}

// ==== 10) gemm2: D = Ydev @ A == outp_pre - mu_k; outp = D*rstd*sc + bi ====
__global__ __launch_bounds__(256) void gemm2_ln_mfma(const short* __restrict__ YdH, const short* __restrict__ YdL,
                                                     const float* __restrict__ imcol,
                                                     const float* __restrict__ pns, const float* __restrict__ pnb,
                                                     float* __restrict__ outp) {
  __shared__ __align__(16) short Ah[64][40];
  __shared__ __align__(16) short Al[64][40];
  __shared__ __align__(16) short Bh[64][40];
  __shared__ __align__(16) short Bl[64][40];
  __shared__ __align__(16) float S[64][68];
  __shared__ float lut[LUT_N];
  __shared__ float rstd[64], sc[64], bi[64];
  const int tid = threadIdx.x;
  const int b = blockIdx.y;
  const int m0 = b * 64, n0 = blockIdx.x * 64;
  const int lane = tid & 63, w = tid >> 6;
  const int fr = lane & 15, quad = lane >> 4;
  const int srow = tid >> 2;
  const int skq  = (tid & 3) * 8;
  const int bcol = tid & 63;
  const int btq  = (tid >> 6) * 8;
  const int colg = n0 + bcol;
  const int mi = colg / W_, mj = colg - (colg / W_) * W_;
  const float imc = imcol[colg];
  if (tid < 64) { sc[tid] = pns[tid]; bi[tid] = pnb[tid]; }
  for (int i = tid; i < LUT_N; i += 256) lut[i] = __expf(-sqrtf((float)i));
  __syncthreads();
  f32x4 acc[4] = {};
  for (int k0 = 0; k0 < N_; k0 += 32) {
    // A-staging: pure 16B loads of pre-split planes
    const size_t aoff = (size_t)(m0 + srow) * N_ + k0 + skq;
    *(bf16x8*)&Ah[srow][skq] = *(const bf16x8*)&YdH[aoff];
    *(bf16x8*)&Al[srow][skq] = *(const bf16x8*)&YdL[aoff];
    bf16x8 bvh, bvl;
#pragma unroll
    for (int j = 0; j < 8; j++) {
      int token = k0 + btq + j;
      int ni = token / W_, nj = token - (token / W_) * W_;
      int dxi = ni - mi, dyi = nj - mj;
      int d2 = dxi * dxi + dyi * dyi;
      short h, l; split_bf(lut[d2] * imc, h, l);
      bvh[j] = h; bvl[j] = l;
    }
    *(bf16x8*)&Bh[bcol][btq] = bvh;
    *(bf16x8*)&Bl[bcol][btq] = bvl;
    __syncthreads();
    bf16x8 afh = *(const bf16x8*)&Ah[w * 16 + fr][quad * 8];
    bf16x8 afl = *(const bf16x8*)&Al[w * 16 + fr][quad * 8];
#pragma unroll
    for (int ns = 0; ns < 4; ns++) {
      bf16x8 bfh = *(const bf16x8*)&Bh[ns * 16 + fr][quad * 8];
      bf16x8 bfl = *(const bf16x8*)&Bl[ns * 16 + fr][quad * 8];
      acc[ns] = __builtin_amdgcn_mfma_f32_16x16x32_bf16(afh, bfh, acc[ns], 0, 0, 0);
      acc[ns] = __builtin_amdgcn_mfma_f32_16x16x32_bf16(afh, bfl, acc[ns], 0, 0, 0);
      acc[ns] = __builtin_amdgcn_mfma_f32_16x16x32_bf16(afl, bfh, acc[ns], 0, 0, 0);
    }
    __syncthreads();
  }
  // S[k_row][m_col]; D has zero k-mean -> var = mean_k(D^2)
#pragma unroll
  for (int ns = 0; ns < 4; ns++)
    *(f32x4*)&S[w * 16 + fr][ns * 16 + quad * 4] = acc[ns];
  __syncthreads();
  if (tid < 64) {
    float ss = 0;
#pragma unroll
    for (int k = 0; k < K_; k++) { float d = S[k][tid]; ss += d * d; }
    rstd[tid] = 1.f / sqrtf(ss / (float)K_ + 1e-5f);
  }
  __syncthreads();
  {
    int c = tid & 63, g = tid >> 6;
#pragma unroll
    for (int i = 0; i < 16; i++) {
      int r = g * 16 + i;
      outp[(size_t)(m0 + r) * N_ + n0 + c] = S[r][c] * rstd[c] * sc[r] + bi[r];
    }
  }
}

extern "C" void kernel_launch(void* const* d_in, const int* in_sizes, int n_in,
                              void* d_out, int out_size, void* d_ws, size_t ws_size,
                              hipStream_t stream) {
  const float* x        = (const float*)d_in[0];
  const float* clusters = (const float*)d_in[1];
  const float* pi       = (const float*)d_in[2];
  const float* cov      = (const float*)d_in[3];
  const float* w_proj   = (const float*)d_in[4];
  const float* nt_scale = (const float*)d_in[5];
  const float* nt_bias  = (const float*)d_in[6];
  const float* pn_scale = (const float*)d_in[7];
  const float* pn_bias  = (const float*)d_in[8];
  float* out = (float*)d_out;
  float* w = (float*)d_ws;
  short* YdH = (short*)(w + OFF_XF);                   // overlays dead xf region
  short* YdL = YdH + (size_t)B_ * K_ * N_;

  k_proj<<<dim3(N_ / 64, B_), 256, 0, stream>>>(x, w_proj, w + OFF_XF);
  k_templ<<<1, K_, 0, stream>>>(clusters, pi, cov, nt_scale, nt_bias,
                                w + OFF_T, w + OFF_T2, w + OFF_LOGPI, w + OFF_I2C);
  k_attn<<<dim3(N_ / 256, B_), 256, 0, stream>>>(w + OFF_XF, w + OFF_T, w + OFF_T2,
                                                 w + OFF_LOGPI, w + OFF_I2C,
                                                 w + OFF_ANT, out + OUT_ATTN, w + OFF_X2);
  k_colsum2<<<B_ * K_, 256, 0, stream>>>(w + OFF_ANT, w + OFF_CS);
  k_pinew<<<B_, K_, 0, stream>>>(w + OFF_CS, pi, out + OUT_PI, w + OFF_ICN);
  // fused t_new + cov (single pass over xf/ant; cov via exact identity)
  k_tnew_cov<<<dim3(K_, B_), 256, 0, stream>>>(w + OFF_ANT, w + OFF_ICN, w + OFF_XF, w + OFF_X2,
                                               clusters, cov, out + OUT_TNEW, out + OUT_COV);
  // amean reuses the x2 buffer (dead after k_tnew_cov)
  k_amean<<<dim3(N_ / 256, B_), 256, 0, stream>>>(w + OFF_ANT, w + OFF_ICN, w + OFF_X2);
  k_msum<<<N_, 256, 0, stream>>>(w + OFF_IMCOL);
  // Ydev = (attn_n - mean_k attn_n) @ A  -> bf16 hi/lo planes (overlay xf)
  gemm1_mfma<<<dim3(N_ / 64, B_), 256, 0, stream>>>(w + OFF_ANT, w + OFF_ICN, w + OFF_X2,
                                                    w + OFF_IMCOL, YdH, YdL);
  // outp = (Ydev @ A) * rstd * sc + bi
  gemm2_ln_mfma<<<dim3(N_ / 64, B_), 256, 0, stream>>>(YdH, YdL, w + OFF_IMCOL,
                                                       pn_scale, pn_bias, out + OUT_OUTP);
}